// Round 3
// baseline (2808.058 us; speedup 1.0000x reference)
//
#include <hip/hip_runtime.h>
#include <hip/hip_bf16.h>
#include <math.h>

#define DIMC 768
#define NHEADS 12
#define WINSZ 14
#define NTOK 196
#define TOKENS 16384

using bf = __hip_bfloat16;
typedef __attribute__((ext_vector_type(4))) float f32x4;
typedef __attribute__((ext_vector_type(8))) short bf16x8;

__device__ inline float b2f(bf h) { return __bfloat162float(h); }
__device__ inline ushort f2bu(float f) {
    bf t = __float2bfloat16(f);
    return __builtin_bit_cast(ushort, t);
}

// ---------------- weight transpose + fp32 -> bf16 convert (tiny) ----------------
__global__ __launch_bounds__(256) void transpose_k(const float* __restrict__ in,
                                                   ushort* __restrict__ out, int R, int C) {
    long i = (long)blockIdx.x * 256 + threadIdx.x;
    if (i >= (long)R * C) return;
    int r = (int)(i / C), c = (int)(i % C);
    out[(long)c * R + r] = f2bu(in[i]);
}

// ---------------- layernorm fp32 in, bf16 out (one row per block, 768 = 3*256) ----------------
__device__ inline float blk_sum(float v, float* wred, int tid) {
    for (int m = 32; m; m >>= 1) v += __shfl_xor(v, m);
    if ((tid & 63) == 0) wred[tid >> 6] = v;
    __syncthreads();
    float r = wred[0] + wred[1] + wred[2] + wred[3];
    __syncthreads();
    return r;
}

__global__ __launch_bounds__(256) void ln_k(const float* __restrict__ x, const float* __restrict__ g,
                                            const float* __restrict__ bb, ushort* __restrict__ out) {
    int row = blockIdx.x, tid = threadIdx.x;
    const float* xr = x + (size_t)row * DIMC;
    __shared__ float wred[4];
    float v0 = xr[tid], v1 = xr[tid + 256], v2 = xr[tid + 512];
    float mean = blk_sum(v0 + v1 + v2, wred, tid) * (1.f / 768.f);
    float d0 = v0 - mean, d1 = v1 - mean, d2 = v2 - mean;
    float var = blk_sum(d0 * d0 + d1 * d1 + d2 * d2, wred, tid) * (1.f / 768.f);
    float rs = rsqrtf(var + 1e-5f);
    ushort* o = out + (size_t)row * DIMC;
    o[tid]       = f2bu(d0 * rs * g[tid]       + bb[tid]);
    o[tid + 256] = f2bu(d1 * rs * g[tid + 256] + bb[tid + 256]);
    o[tid + 512] = f2bu(d2 * rs * g[tid + 512] + bb[tid + 512]);
}

// ---------------- bf16 MFMA GEMM, 64x64 tile; Bt pre-transposed [N][K] bf16 ----------------
// M = 16384 always (multiple of 64) -> no row guards. Bias is fp32.
enum { EPI_BIAS = 0, EPI_GELU = 1, EPI_PROJRES = 2, EPI_ACC = 3, EPI_RESOUT = 4 };

template <int EPI>
__global__ __launch_bounds__(256) void gemm_k(const ushort* __restrict__ A, int lda,
                                              const ushort* __restrict__ Bt, int ldb,
                                              const float* __restrict__ bias,
                                              ushort* __restrict__ outb,        // bf16 out
                                              float* __restrict__ outf,         // fp32 out
                                              const float* __restrict__ xorig,  // fp32 residual in
                                              float* __restrict__ x2,           // fp32 acc
                                              int N, int K) {
    __shared__ ushort lA[64 * 40];   // +8 pad: 2-way bank alias only (free per m136)
    __shared__ ushort lB[64 * 40];
    const int bm = blockIdx.y * 64, bn = blockIdx.x * 64;
    const int tid = threadIdx.x, wave = tid >> 6, lane = tid & 63;
    const int lm = lane & 15, quad = lane >> 4;
    const int srow = tid >> 2, scol = (tid & 3) * 8;

    f32x4 acc[4];
#pragma unroll
    for (int i = 0; i < 4; ++i) acc[i] = (f32x4){0.f, 0.f, 0.f, 0.f};

    const ushort* Ap = A + (size_t)(bm + srow) * lda + scol;
    const ushort* Bp = Bt + (size_t)(bn + srow) * ldb + scol;

    for (int k0 = 0; k0 < K; k0 += 32) {
        uint4 av = *(const uint4*)(Ap + k0);
        uint4 bv = *(const uint4*)(Bp + k0);
        *(uint4*)&lA[srow * 40 + scol] = av;
        *(uint4*)&lB[srow * 40 + scol] = bv;
        __syncthreads();
        bf16x8 af = *(const bf16x8*)&lA[(wave * 16 + lm) * 40 + quad * 8];
#pragma unroll
        for (int nb = 0; nb < 4; ++nb) {
            bf16x8 bfv = *(const bf16x8*)&lB[(nb * 16 + lm) * 40 + quad * 8];
            acc[nb] = __builtin_amdgcn_mfma_f32_16x16x32_bf16(af, bfv, acc[nb], 0, 0, 0);
        }
        __syncthreads();
    }

#pragma unroll
    for (int nb = 0; nb < 4; ++nb) {
        int col = bn + nb * 16 + lm;
        float bvl = (EPI == EPI_ACC) ? 0.f : bias[col];
#pragma unroll
        for (int i = 0; i < 4; ++i) {
            int row = bm + wave * 16 + quad * 4 + i;
            float v = acc[nb][i] + bvl;
            size_t idx = (size_t)row * N + col;
            if constexpr (EPI == EPI_BIAS) {
                outb[idx] = f2bu(v);
            } else if constexpr (EPI == EPI_GELU) {
                outb[idx] = f2bu(0.5f * v * (1.f + erff(v * 0.70710678118f)));
            } else if constexpr (EPI == EPI_PROJRES) {
                x2[idx] = xorig[idx] + v;               // x2 = x + proj(attn), exact fp32 residual
            } else if constexpr (EPI == EPI_ACC) {
                x2[idx] += v;                           // accumulate MLP2 chunk
            } else {                                    // EPI_RESOUT: final chunk, fp32 out
                outf[idx] = x2[idx] + v;
            }
        }
    }
}

// ---------------- fused attention per (window, head); pad-token K/V = qkv bias slice ----------------
__global__ __launch_bounds__(256) void attn_k(const ushort* __restrict__ qkv,   // bf16 [16384][2304]
                                              const float* __restrict__ qkvb,   // fp32 [2304]
                                              const float* __restrict__ relh,
                                              const float* __restrict__ relw,
                                              ushort* __restrict__ aout) {      // bf16 [16384][768]
    const int win = blockIdx.x / NHEADS, head = blockIdx.x % NHEADS;
    const int b = win / 25, wi = win % 25, wr = wi / 5, wc = wi % 5;
    const int hmax = (wr == 4) ? 8 : WINSZ, wmax = (wc == 4) ? 8 : WINSZ;
    const int hoff = head * 64;
    __shared__ ushort ks[NTOK * 72];   // stride 72: 16B-aligned rows, non-pow2 banks
    __shared__ ushort vs[NTOK * 72];
    __shared__ float qrow[64];
    __shared__ float p[NTOK];
    __shared__ float qdh[WINSZ], qdw[WINSZ];
    __shared__ float wredm[4], wreds[4];
    const int tid = threadIdx.x, lane = tid & 63, wave = tid >> 6;

    for (int t = tid; t < NTOK * 8; t += 256) {
        int n = t >> 3, c8 = (t & 7) * 8;
        int kh = n / WINSZ, kw = n % WINSZ;
        if (kh < hmax && kw < wmax) {
            size_t tok = ((size_t)(b * 64 + wr * WINSZ + kh) * 64 + wc * WINSZ + kw) * 2304;
            *(uint4*)&ks[n * 72 + c8] = *(const uint4*)(qkv + tok + 768 + hoff + c8);
            *(uint4*)&vs[n * 72 + c8] = *(const uint4*)(qkv + tok + 1536 + hoff + c8);
        } else {  // pad token: LN output is 0 -> k/v = qkv bias slice
            for (int j = 0; j < 8; ++j) {
                ks[n * 72 + c8 + j] = f2bu(qkvb[768 + hoff + c8 + j]);
                vs[n * 72 + c8 + j] = f2bu(qkvb[1536 + hoff + c8 + j]);
            }
        }
    }
    __syncthreads();

    for (int nq = 0; nq < NTOK; ++nq) {
        const int qh = nq / WINSZ, qw = nq % WINSZ;
        if (qh >= hmax || qw >= wmax) continue;   // block-uniform skip of pad q rows
        const size_t qtok = (size_t)(b * 64 + wr * WINSZ + qh) * 64 + wc * WINSZ + qw;
        if (tid < 64) qrow[tid] = __uint_as_float(((uint)qkv[qtok * 2304 + hoff + tid]) << 16);
        __syncthreads();
        if (tid < 28) {  // 28 dot-products vs rel_pos tables (bias uses UNscaled q)
            int kk = (tid < 14) ? tid : tid - 14;
            const float* rp = (tid < 14) ? (relh + (size_t)(qh - kk + 13) * 64)
                                         : (relw + (size_t)(qw - kk + 13) * 64);
            float s = 0.f;
            for (int c = 0; c < 64; ++c) s += qrow[c] * rp[c];
            if (tid < 14) qdh[kk] = s; else qdw[kk] = s;
        }
        __syncthreads();
        float sc = -1e30f;
        if (tid < NTOK) {
            float s = 0.f;
            const uint4* kp = (const uint4*)&ks[tid * 72];
#pragma unroll
            for (int g = 0; g < 8; ++g) {
                uint4 u = kp[g];
                s += __uint_as_float(u.x << 16)         * qrow[g * 8 + 0];
                s += __uint_as_float(u.x & 0xffff0000u) * qrow[g * 8 + 1];
                s += __uint_as_float(u.y << 16)         * qrow[g * 8 + 2];
                s += __uint_as_float(u.y & 0xffff0000u) * qrow[g * 8 + 3];
                s += __uint_as_float(u.z << 16)         * qrow[g * 8 + 4];
                s += __uint_as_float(u.z & 0xffff0000u) * qrow[g * 8 + 5];
                s += __uint_as_float(u.w << 16)         * qrow[g * 8 + 6];
                s += __uint_as_float(u.w & 0xffff0000u) * qrow[g * 8 + 7];
            }
            sc = 0.125f * s + qdh[tid / WINSZ] + qdw[tid % WINSZ];
        }
        float m = sc;
        for (int msk = 32; msk; msk >>= 1) m = fmaxf(m, __shfl_xor(m, msk));
        if (lane == 0) wredm[wave] = m;
        __syncthreads();
        m = fmaxf(fmaxf(wredm[0], wredm[1]), fmaxf(wredm[2], wredm[3]));
        float e = (tid < NTOK) ? expf(sc - m) : 0.f;
        if (tid < NTOK) p[tid] = e;
        float ssum = e;
        for (int msk = 32; msk; msk >>= 1) ssum += __shfl_xor(ssum, msk);
        if (lane == 0) wreds[wave] = ssum;
        __syncthreads();
        float inv = 1.f / (wreds[0] + wreds[1] + wreds[2] + wreds[3]);
        if (tid < 64) {
            float o = 0.f;
            for (int k = 0; k < NTOK; ++k)
                o += p[k] * __uint_as_float(((uint)vs[k * 72 + tid]) << 16);
            aout[qtok * DIMC + hoff + tid] = f2bu(o * inv);
        }
        __syncthreads();
    }
}

extern "C" void kernel_launch(void* const* d_in, const int* in_sizes, int n_in,
                              void* d_out, int out_size, void* d_ws, size_t ws_size,
                              hipStream_t stream) {
    const float* x      = (const float*)d_in[0];
    const float* n1g    = (const float*)d_in[1];
    const float* n1b    = (const float*)d_in[2];
    const float* qkv_w  = (const float*)d_in[3];
    const float* qkv_b  = (const float*)d_in[4];
    const float* proj_w = (const float*)d_in[5];
    const float* proj_b = (const float*)d_in[6];
    const float* relh   = (const float*)d_in[7];
    const float* relw   = (const float*)d_in[8];
    const float* n2g    = (const float*)d_in[9];
    const float* n2b    = (const float*)d_in[10];
    const float* w1     = (const float*)d_in[11];
    const float* b1     = (const float*)d_in[12];
    const float* w2     = (const float*)d_in[13];
    const float* b2     = (const float*)d_in[14];
    float* out = (float*)d_out;

    char* ws = (char*)d_ws;
    size_t off = 0;
    auto alloc = [&](size_t bytes) -> void* {
        void* p = ws + off;
        off += (bytes + 255) & ~(size_t)255;
        return p;
    };

    ushort* lnbuf  = (ushort*)alloc((size_t)TOKENS * DIMC * 2);    // 25.2 MB: LN1 out / aout / LN2 out
    ushort* qkvbuf = (ushort*)alloc((size_t)TOKENS * 2304 * 2);    // 75.5 MB: qkv, later MLP hidden chunk
    float* x2      = (float*)alloc((size_t)TOKENS * DIMC * 4);     // 50.3 MB fp32 residual + MLP acc
    ushort* qkvT   = (ushort*)alloc((size_t)2304 * 768 * 2);
    ushort* projT  = (ushort*)alloc((size_t)768 * 768 * 2);
    ushort* w1T    = (ushort*)alloc((size_t)3072 * 768 * 2);
    ushort* w2T    = (ushort*)alloc((size_t)768 * 3072 * 2);
    ushort* aout   = lnbuf;    // overlays LN1 output (dead after qkv GEMM)
    ushort* hc     = qkvbuf;   // MLP hidden chunk overlays qkv (dead after attention)

    transpose_k<<<(768 * 2304 + 255) / 256, 256, 0, stream>>>(qkv_w, qkvT, 768, 2304);
    transpose_k<<<(768 * 768 + 255) / 256, 256, 0, stream>>>(proj_w, projT, 768, 768);
    transpose_k<<<(768 * 3072 + 255) / 256, 256, 0, stream>>>(w1, w1T, 768, 3072);
    transpose_k<<<(3072 * 768 + 255) / 256, 256, 0, stream>>>(w2, w2T, 3072, 768);

    ln_k<<<TOKENS, 256, 0, stream>>>(x, n1g, n1b, lnbuf);

    dim3 gq(2304 / 64, TOKENS / 64);
    gemm_k<EPI_BIAS><<<gq, 256, 0, stream>>>(lnbuf, DIMC, qkvT, DIMC, qkv_b, qkvbuf,
                                             nullptr, nullptr, nullptr, 2304, DIMC);

    attn_k<<<100 * NHEADS, 256, 0, stream>>>(qkvbuf, qkv_b, relh, relw, aout);

    dim3 gp(DIMC / 64, TOKENS / 64);
    gemm_k<EPI_PROJRES><<<gp, 256, 0, stream>>>(aout, DIMC, projT, DIMC, proj_b, nullptr,
                                                nullptr, x, x2, DIMC, DIMC);

    ln_k<<<TOKENS, 256, 0, stream>>>(x2, n2g, n2b, lnbuf);

    for (int c = 0; c < 4; ++c) {
        gemm_k<EPI_GELU><<<gp, 256, 0, stream>>>(lnbuf, DIMC, w1T + (size_t)c * 768 * 768, DIMC,
                                                 b1 + c * 768, hc, nullptr, nullptr, nullptr,
                                                 DIMC, DIMC);
        if (c < 3)
            gemm_k<EPI_ACC><<<gp, 256, 0, stream>>>(hc, DIMC, w2T + c * 768, 3072,
                                                    b2, nullptr, nullptr, nullptr, x2, DIMC, DIMC);
        else
            gemm_k<EPI_RESOUT><<<gp, 256, 0, stream>>>(hc, DIMC, w2T + c * 768, 3072,
                                                       b2, nullptr, out, nullptr, x2, DIMC, DIMC);
    }
}

// Round 4
// 978.885 us; speedup vs baseline: 2.8686x; 2.8686x over previous
//
#include <hip/hip_runtime.h>
#include <hip/hip_bf16.h>
#include <math.h>

#define DIMC 768
#define NHEADS 12
#define WINSZ 14
#define NTOK 196
#define TOKENS 16384

using bf = __hip_bfloat16;
typedef __attribute__((ext_vector_type(4))) float f32x4;
typedef __attribute__((ext_vector_type(8))) short bf16x8;

__device__ inline float bfu2f(ushort u) { return __uint_as_float((uint)u << 16); }
__device__ inline ushort f2bu(float f) {
    bf t = __float2bfloat16(f);
    return __builtin_bit_cast(ushort, t);
}

// ---------------- weight transpose + fp32 -> bf16 convert (tiny) ----------------
__global__ __launch_bounds__(256) void transpose_k(const float* __restrict__ in,
                                                   ushort* __restrict__ out, int R, int C) {
    long i = (long)blockIdx.x * 256 + threadIdx.x;
    if (i >= (long)R * C) return;
    int r = (int)(i / C), c = (int)(i % C);
    out[(long)c * R + r] = f2bu(in[i]);
}

// ---------------- layernorm fp32 in, bf16 out ----------------
__device__ inline float blk_sum(float v, float* wred, int tid) {
    for (int m = 32; m; m >>= 1) v += __shfl_xor(v, m);
    if ((tid & 63) == 0) wred[tid >> 6] = v;
    __syncthreads();
    float r = wred[0] + wred[1] + wred[2] + wred[3];
    __syncthreads();
    return r;
}

__global__ __launch_bounds__(256) void ln_k(const float* __restrict__ x, const float* __restrict__ g,
                                            const float* __restrict__ bb, ushort* __restrict__ out) {
    int row = blockIdx.x, tid = threadIdx.x;
    const float* xr = x + (size_t)row * DIMC;
    __shared__ float wred[4];
    float v0 = xr[tid], v1 = xr[tid + 256], v2 = xr[tid + 512];
    float mean = blk_sum(v0 + v1 + v2, wred, tid) * (1.f / 768.f);
    float d0 = v0 - mean, d1 = v1 - mean, d2 = v2 - mean;
    float var = blk_sum(d0 * d0 + d1 * d1 + d2 * d2, wred, tid) * (1.f / 768.f);
    float rs = rsqrtf(var + 1e-5f);
    ushort* o = out + (size_t)row * DIMC;
    o[tid]       = f2bu(d0 * rs * g[tid]       + bb[tid]);
    o[tid + 256] = f2bu(d1 * rs * g[tid + 256] + bb[tid + 256]);
    o[tid + 512] = f2bu(d2 * rs * g[tid + 512] + bb[tid + 512]);
}

// ---------------- bf16 MFMA GEMM, 64x64 tile (unchanged from round 3) ----------------
enum { EPI_BIAS = 0, EPI_GELU = 1, EPI_PROJRES = 2, EPI_ACC = 3, EPI_RESOUT = 4 };

template <int EPI>
__global__ __launch_bounds__(256) void gemm_k(const ushort* __restrict__ A, int lda,
                                              const ushort* __restrict__ Bt, int ldb,
                                              const float* __restrict__ bias,
                                              ushort* __restrict__ outb,
                                              float* __restrict__ outf,
                                              const float* __restrict__ xorig,
                                              float* __restrict__ x2,
                                              int N, int K) {
    __shared__ ushort lA[64 * 40];
    __shared__ ushort lB[64 * 40];
    const int bm = blockIdx.y * 64, bn = blockIdx.x * 64;
    const int tid = threadIdx.x, wave = tid >> 6, lane = tid & 63;
    const int lm = lane & 15, quad = lane >> 4;
    const int srow = tid >> 2, scol = (tid & 3) * 8;

    f32x4 acc[4];
#pragma unroll
    for (int i = 0; i < 4; ++i) acc[i] = (f32x4){0.f, 0.f, 0.f, 0.f};

    const ushort* Ap = A + (size_t)(bm + srow) * lda + scol;
    const ushort* Bp = Bt + (size_t)(bn + srow) * ldb + scol;

    for (int k0 = 0; k0 < K; k0 += 32) {
        uint4 av = *(const uint4*)(Ap + k0);
        uint4 bv = *(const uint4*)(Bp + k0);
        *(uint4*)&lA[srow * 40 + scol] = av;
        *(uint4*)&lB[srow * 40 + scol] = bv;
        __syncthreads();
        bf16x8 af = *(const bf16x8*)&lA[(wave * 16 + lm) * 40 + quad * 8];
#pragma unroll
        for (int nb = 0; nb < 4; ++nb) {
            bf16x8 bfv = *(const bf16x8*)&lB[(nb * 16 + lm) * 40 + quad * 8];
            acc[nb] = __builtin_amdgcn_mfma_f32_16x16x32_bf16(af, bfv, acc[nb], 0, 0, 0);
        }
        __syncthreads();
    }

#pragma unroll
    for (int nb = 0; nb < 4; ++nb) {
        int col = bn + nb * 16 + lm;
        float bvl = (EPI == EPI_ACC) ? 0.f : bias[col];
#pragma unroll
        for (int i = 0; i < 4; ++i) {
            int row = bm + wave * 16 + quad * 4 + i;
            float v = acc[nb][i] + bvl;
            size_t idx = (size_t)row * N + col;
            if constexpr (EPI == EPI_BIAS) {
                outb[idx] = f2bu(v);
            } else if constexpr (EPI == EPI_GELU) {
                outb[idx] = f2bu(0.5f * v * (1.f + erff(v * 0.70710678118f)));
            } else if constexpr (EPI == EPI_PROJRES) {
                x2[idx] = xorig[idx] + v;
            } else if constexpr (EPI == EPI_ACC) {
                x2[idx] += v;
            } else {
                outf[idx] = x2[idx] + v;
            }
        }
    }
}

// ---------------- MFMA attention: one block per (window, head), 4 waves ----------------
// Keys padded n' = kh*16+kw (224), kw>=14 masked. Row-tiles = one qh each (16 rows, qw 0..15).
// Scale 0.125 folded into K at staging. rel_h/rel_w bias via Q·RelH^T / Q·RelW^T MFMA +
// LDS-broadcast (dh, wave-uniform col per tile) / ds_bpermute (dw) redistribution.
__global__ __launch_bounds__(256) void attn_k(const ushort* __restrict__ qkv,   // bf16 [16384][2304]
                                              const float* __restrict__ qkvb,   // fp32 [2304]
                                              const float* __restrict__ relh,   // fp32 [27][64]
                                              const float* __restrict__ relw,   // fp32 [27][64]
                                              ushort* __restrict__ aout) {      // bf16 [16384][768]
    const int win = blockIdx.x / NHEADS, head = blockIdx.x % NHEADS;
    const int b = win / 25, wi = win % 25, wr = wi / 5, wc = wi % 5;
    const int hmax = (wr == 4) ? 8 : WINSZ, wmax = (wc == 4) ? 8 : WINSZ;
    const int hoff = head * 64;
    const int tid = threadIdx.x, wave = tid >> 6, lane = tid & 63;
    const int c = lane & 15, quad = lane >> 4;

    __shared__ ushort Ksw[224 * 64];     // K' = 0.125*K, chunk-XOR swizzled (28 KB)
    __shared__ ushort vTs[64 * 232];     // V transposed [dim][key], stride 232 (29 KB)
    __shared__ ushort wscr[4][640];      // per-wave scratch: dh_s[16][28] then pscr[16][40]

    // ---- stage K' (scaled, swizzled); fake cols kw>=14 zeroed ----
    for (int t = tid; t < 224 * 8; t += 256) {
        int n = t >> 3, ck = t & 7;
        int kh = n >> 4, kw = n & 15;
        union { uint4 u; ushort s[8]; } vals;
        if (kw < WINSZ) {
            if (kh < hmax && kw < wmax) {
                size_t tok = ((size_t)(b * 64 + wr * WINSZ + kh) * 64 + wc * WINSZ + kw);
                union { uint4 u; ushort s[8]; } raw;
                raw.u = *(const uint4*)(qkv + tok * 2304 + 768 + hoff + ck * 8);
#pragma unroll
                for (int j = 0; j < 8; ++j) vals.s[j] = f2bu(0.125f * bfu2f(raw.s[j]));
            } else {  // pad token: k = qkv bias slice
#pragma unroll
                for (int j = 0; j < 8; ++j) vals.s[j] = f2bu(0.125f * qkvb[768 + hoff + ck * 8 + j]);
            }
        } else {
            vals.u = (uint4){0u, 0u, 0u, 0u};
        }
        *(uint4*)&Ksw[n * 64 + ((ck ^ (n & 7)) * 8)] = vals.u;
    }
    // ---- stage V^T; fake keys zeroed ----
    for (int u = tid; u < 64 * 28; u += 256) {
        int d = u / 28, kc = u % 28;
        union { uint4 u4; ushort s[8]; } vals;
#pragma unroll
        for (int j = 0; j < 8; ++j) {
            int n = kc * 8 + j, kh = n >> 4, kw = n & 15;
            ushort v = 0;
            if (kw < WINSZ) {
                if (kh < hmax && kw < wmax) {
                    size_t tok = ((size_t)(b * 64 + wr * WINSZ + kh) * 64 + wc * WINSZ + kw);
                    v = qkv[tok * 2304 + 1536 + hoff + d];
                } else {
                    v = f2bu(qkvb[1536 + hoff + d]);
                }
            }
            vals.s[j] = v;
        }
        *(uint4*)&vTs[d * 232 + kc * 8] = vals.u4;
    }
    __syncthreads();   // the ONLY block barrier

    // ---- preload RelH / RelW B-fragments (constant per wave) ----
    bf16x8 rhB[2][2], rwB[2][2];
#pragma unroll
    for (int nt = 0; nt < 2; ++nt) {
        int j = nt * 16 + c; if (j > 26) j = 26;
#pragma unroll
        for (int ks = 0; ks < 2; ++ks) {
            const float* ph = relh + (size_t)j * 64 + ks * 32 + quad * 8;
            const float* pw = relw + (size_t)j * 64 + ks * 32 + quad * 8;
            bf16x8 h, w;
#pragma unroll
            for (int e = 0; e < 8; ++e) {
                h[e] = (short)f2bu(ph[e]);
                w[e] = (short)f2bu(pw[e]);
            }
            rhB[nt][ks] = h; rwB[nt][ks] = w;
        }
    }

    ushort* scr = &wscr[wave][0];
    const int lane48 = lane & 48;

    for (int qh = wave; qh < hmax; qh += 4) {
        // Q A-fragments (unscaled; scale folded into K')
        int qw = c < wmax ? c : (wmax - 1);   // clamp pad rows (discarded)
        size_t qtok = ((size_t)(b * 64 + wr * WINSZ + qh) * 64 + wc * WINSZ + qw);
        bf16x8 aq0 = *(const bf16x8*)(qkv + qtok * 2304 + hoff + quad * 8);
        bf16x8 aq1 = *(const bf16x8*)(qkv + qtok * 2304 + hoff + 32 + quad * 8);

        // D_h = Q·RelH^T, D_w = Q·RelW^T  [16 rows][27 cols]
        f32x4 z = (f32x4){0.f, 0.f, 0.f, 0.f};
        f32x4 dh0 = __builtin_amdgcn_mfma_f32_16x16x32_bf16(aq0, rhB[0][0], z, 0, 0, 0);
        dh0 = __builtin_amdgcn_mfma_f32_16x16x32_bf16(aq1, rhB[0][1], dh0, 0, 0, 0);
        f32x4 dh1 = __builtin_amdgcn_mfma_f32_16x16x32_bf16(aq0, rhB[1][0], z, 0, 0, 0);
        dh1 = __builtin_amdgcn_mfma_f32_16x16x32_bf16(aq1, rhB[1][1], dh1, 0, 0, 0);
        f32x4 dw0 = __builtin_amdgcn_mfma_f32_16x16x32_bf16(aq0, rwB[0][0], z, 0, 0, 0);
        dw0 = __builtin_amdgcn_mfma_f32_16x16x32_bf16(aq1, rwB[0][1], dw0, 0, 0, 0);
        f32x4 dw1 = __builtin_amdgcn_mfma_f32_16x16x32_bf16(aq0, rwB[1][0], z, 0, 0, 0);
        dw1 = __builtin_amdgcn_mfma_f32_16x16x32_bf16(aq1, rwB[1][1], dw1, 0, 0, 0);

        // write D_h to per-wave scratch [16][28] bf16 (C layout: row=quad*4+i, col=c)
#pragma unroll
        for (int i = 0; i < 4; ++i) {
            scr[(quad * 4 + i) * 28 + c] = f2bu(dh0[i]);
            if (c < 12) scr[(quad * 4 + i) * 28 + 16 + c] = f2bu(dh1[i]);
        }

        // dw bias per row via bpermute: bias_w[i] = D_w[m = quad*4+i][j = m - c + 13]
        float bw[4];
#pragma unroll
        for (int i = 0; i < 4; ++i) {
            int m = quad * 4 + i;
            int j = m - c + 13; int jc = j < 0 ? 0 : j;
            int addr = (lane48 | (jc & 15)) << 2;
            int t0 = __builtin_amdgcn_ds_bpermute(addr, __float_as_int(dw0[i]));
            int t1 = __builtin_amdgcn_ds_bpermute(addr, __float_as_int(dw1[i]));
            bw[i] = (jc >= 16) ? __int_as_float(t1) : __int_as_float(t0);
        }

        // S = Q·K'^T  (14 N-tiles == kh), + bias, + mask
        f32x4 s[14];
        const int n7base = (c & 7);
#pragma unroll
        for (int kh = 0; kh < 14; ++kh) {
            int n = kh * 16 + c;
            int n7 = n & 7;
            bf16x8 kb0 = *(const bf16x8*)&Ksw[n * 64 + ((0 * 4 + quad) ^ n7) * 8];
            bf16x8 kb1 = *(const bf16x8*)&Ksw[n * 64 + ((1 * 4 + quad) ^ n7) * 8];
            f32x4 acc = __builtin_amdgcn_mfma_f32_16x16x32_bf16(aq0, kb0, z, 0, 0, 0);
            acc = __builtin_amdgcn_mfma_f32_16x16x32_bf16(aq1, kb1, acc, 0, 0, 0);
            int jstar = qh + 13 - kh;   // wave-uniform
#pragma unroll
            for (int i = 0; i < 4; ++i) {
                float dh = bfu2f(scr[(quad * 4 + i) * 28 + jstar]);  // broadcast read
                float v = acc[i] + dh + bw[i];
                acc[i] = (c < WINSZ) ? v : -1e30f;
            }
            s[kh] = acc;
        }

        // softmax per row (reduce over 14 frags + 16 lanes of quad)
        float inv[4];
#pragma unroll
        for (int i = 0; i < 4; ++i) {
            float mx = s[0][i];
#pragma unroll
            for (int kh = 1; kh < 14; ++kh) mx = fmaxf(mx, s[kh][i]);
            mx = fmaxf(mx, __shfl_xor(mx, 1));
            mx = fmaxf(mx, __shfl_xor(mx, 2));
            mx = fmaxf(mx, __shfl_xor(mx, 4));
            mx = fmaxf(mx, __shfl_xor(mx, 8));
            float sum = 0.f;
#pragma unroll
            for (int kh = 0; kh < 14; ++kh) {
                float e = __expf(s[kh][i] - mx);
                s[kh][i] = e;
                sum += e;
            }
            sum += __shfl_xor(sum, 1);
            sum += __shfl_xor(sum, 2);
            sum += __shfl_xor(sum, 4);
            sum += __shfl_xor(sum, 8);
            inv[i] = 1.f / sum;
        }

        // PV: O[16][64], K-dim = 224 keys in 7 chunks of 32 (2 kh-tiles each)
        f32x4 o[4] = {z, z, z, z};
#pragma unroll
        for (int cc = 0; cc < 7; ++cc) {
            // write P chunk (bf16) to scratch [16][40]
#pragma unroll
            for (int i = 0; i < 4; ++i) {
                scr[(quad * 4 + i) * 40 + c]      = f2bu(s[2 * cc][i] * inv[i]);
                scr[(quad * 4 + i) * 40 + 16 + c] = f2bu(s[2 * cc + 1][i] * inv[i]);
            }
            bf16x8 ap = *(const bf16x8*)&scr[c * 40 + quad * 8];
#pragma unroll
            for (int vt = 0; vt < 4; ++vt) {
                bf16x8 vb = *(const bf16x8*)&vTs[(vt * 16 + c) * 232 + cc * 32 + quad * 8];
                o[vt] = __builtin_amdgcn_mfma_f32_16x16x32_bf16(ap, vb, o[vt], 0, 0, 0);
            }
        }

        // write O rows (qw' = quad*4+i < wmax)
#pragma unroll
        for (int i = 0; i < 4; ++i) {
            int qwp = quad * 4 + i;
            if (qwp < wmax) {
                size_t otok = ((size_t)(b * 64 + wr * WINSZ + qh) * 64 + wc * WINSZ + qwp);
#pragma unroll
                for (int vt = 0; vt < 4; ++vt)
                    aout[otok * 768 + hoff + vt * 16 + c] = f2bu(o[vt][i]);
            }
        }
    }
}

extern "C" void kernel_launch(void* const* d_in, const int* in_sizes, int n_in,
                              void* d_out, int out_size, void* d_ws, size_t ws_size,
                              hipStream_t stream) {
    const float* x      = (const float*)d_in[0];
    const float* n1g    = (const float*)d_in[1];
    const float* n1b    = (const float*)d_in[2];
    const float* qkv_w  = (const float*)d_in[3];
    const float* qkv_b  = (const float*)d_in[4];
    const float* proj_w = (const float*)d_in[5];
    const float* proj_b = (const float*)d_in[6];
    const float* relh   = (const float*)d_in[7];
    const float* relw   = (const float*)d_in[8];
    const float* n2g    = (const float*)d_in[9];
    const float* n2b    = (const float*)d_in[10];
    const float* w1     = (const float*)d_in[11];
    const float* b1     = (const float*)d_in[12];
    const float* w2     = (const float*)d_in[13];
    const float* b2     = (const float*)d_in[14];
    float* out = (float*)d_out;

    char* ws = (char*)d_ws;
    size_t off = 0;
    auto alloc = [&](size_t bytes) -> void* {
        void* p = ws + off;
        off += (bytes + 255) & ~(size_t)255;
        return p;
    };

    ushort* lnbuf  = (ushort*)alloc((size_t)TOKENS * DIMC * 2);
    ushort* qkvbuf = (ushort*)alloc((size_t)TOKENS * 2304 * 2);
    float* x2      = (float*)alloc((size_t)TOKENS * DIMC * 4);
    ushort* qkvT   = (ushort*)alloc((size_t)2304 * 768 * 2);
    ushort* projT  = (ushort*)alloc((size_t)768 * 768 * 2);
    ushort* w1T    = (ushort*)alloc((size_t)3072 * 768 * 2);
    ushort* w2T    = (ushort*)alloc((size_t)768 * 3072 * 2);
    ushort* aout   = lnbuf;
    ushort* hc     = qkvbuf;

    transpose_k<<<(768 * 2304 + 255) / 256, 256, 0, stream>>>(qkv_w, qkvT, 768, 2304);
    transpose_k<<<(768 * 768 + 255) / 256, 256, 0, stream>>>(proj_w, projT, 768, 768);
    transpose_k<<<(768 * 3072 + 255) / 256, 256, 0, stream>>>(w1, w1T, 768, 3072);
    transpose_k<<<(3072 * 768 + 255) / 256, 256, 0, stream>>>(w2, w2T, 3072, 768);

    ln_k<<<TOKENS, 256, 0, stream>>>(x, n1g, n1b, lnbuf);

    dim3 gq(2304 / 64, TOKENS / 64);
    gemm_k<EPI_BIAS><<<gq, 256, 0, stream>>>(lnbuf, DIMC, qkvT, DIMC, qkv_b, qkvbuf,
                                             nullptr, nullptr, nullptr, 2304, DIMC);

    attn_k<<<100 * NHEADS, 256, 0, stream>>>(qkvbuf, qkv_b, relh, relw, aout);

    dim3 gp(DIMC / 64, TOKENS / 64);
    gemm_k<EPI_PROJRES><<<gp, 256, 0, stream>>>(aout, DIMC, projT, DIMC, proj_b, nullptr,
                                                nullptr, x, x2, DIMC, DIMC);

    ln_k<<<TOKENS, 256, 0, stream>>>(x2, n2g, n2b, lnbuf);

    for (int c = 0; c < 4; ++c) {
        gemm_k<EPI_GELU><<<gp, 256, 0, stream>>>(lnbuf, DIMC, w1T + (size_t)c * 768 * 768, DIMC,
                                                 b1 + c * 768, hc, nullptr, nullptr, nullptr,
                                                 DIMC, DIMC);
        if (c < 3)
            gemm_k<EPI_ACC><<<gp, 256, 0, stream>>>(hc, DIMC, w2T + c * 768, 3072,
                                                    b2, nullptr, nullptr, nullptr, x2, DIMC, DIMC);
        else
            gemm_k<EPI_RESOUT><<<gp, 256, 0, stream>>>(hc, DIMC, w2T + c * 768, 3072,
                                                       b2, nullptr, out, nullptr, x2, DIMC, DIMC);
    }
}

// Round 5
// 773.996 us; speedup vs baseline: 3.6280x; 1.2647x over previous
//
#include <hip/hip_runtime.h>
#include <hip/hip_bf16.h>
#include <math.h>

#define DIMC 768
#define NHEADS 12
#define WINSZ 14
#define NTOK 196
#define TOKENS 16384

using bf = __hip_bfloat16;
typedef __attribute__((ext_vector_type(4))) float f32x4;
typedef __attribute__((ext_vector_type(8))) short bf16x8;

typedef __attribute__((address_space(3))) void lds_void_t;
typedef const __attribute__((address_space(1))) void gmem_void_t;

__device__ inline float bfu2f(ushort u) { return __uint_as_float((uint)u << 16); }
__device__ inline ushort f2bu(float f) {
    bf t = __float2bfloat16(f);
    return __builtin_bit_cast(ushort, t);
}

// ---------------- weight transpose + fp32 -> bf16 convert (tiny) ----------------
__global__ __launch_bounds__(256) void transpose_k(const float* __restrict__ in,
                                                   ushort* __restrict__ out, int R, int C) {
    long i = (long)blockIdx.x * 256 + threadIdx.x;
    if (i >= (long)R * C) return;
    int r = (int)(i / C), c = (int)(i % C);
    out[(long)c * R + r] = f2bu(in[i]);
}

// ---------------- layernorm fp32 in, bf16 out ----------------
__device__ inline float blk_sum(float v, float* wred, int tid) {
    for (int m = 32; m; m >>= 1) v += __shfl_xor(v, m);
    if ((tid & 63) == 0) wred[tid >> 6] = v;
    __syncthreads();
    float r = wred[0] + wred[1] + wred[2] + wred[3];
    __syncthreads();
    return r;
}

__global__ __launch_bounds__(256) void ln_k(const float* __restrict__ x, const float* __restrict__ g,
                                            const float* __restrict__ bb, ushort* __restrict__ out) {
    int row = blockIdx.x, tid = threadIdx.x;
    const float* xr = x + (size_t)row * DIMC;
    __shared__ float wred[4];
    float v0 = xr[tid], v1 = xr[tid + 256], v2 = xr[tid + 512];
    float mean = blk_sum(v0 + v1 + v2, wred, tid) * (1.f / 768.f);
    float d0 = v0 - mean, d1 = v1 - mean, d2 = v2 - mean;
    float var = blk_sum(d0 * d0 + d1 * d1 + d2 * d2, wred, tid) * (1.f / 768.f);
    float rs = rsqrtf(var + 1e-5f);
    ushort* o = out + (size_t)row * DIMC;
    o[tid]       = f2bu(d0 * rs * g[tid]       + bb[tid]);
    o[tid + 256] = f2bu(d1 * rs * g[tid + 256] + bb[tid + 256]);
    o[tid + 512] = f2bu(d2 * rs * g[tid + 512] + bb[tid + 512]);
}

// ---------------- bf16 MFMA GEMM, m97 structure: 128x128 tile, global_load_lds ----------------
// M,N multiples of 128; K multiple of 32. Bt pre-transposed [N][K] bf16. Bias fp32.
enum { EPI_BIAS = 0, EPI_GELU = 1, EPI_PROJRES = 2, EPI_ACC = 3, EPI_RESOUT = 4 };

template <int EPI>
__global__ __launch_bounds__(256) void gemm_k(const ushort* __restrict__ A, int lda,
                                              const ushort* __restrict__ Bt, int ldb,
                                              const float* __restrict__ bias,
                                              ushort* __restrict__ outb,
                                              float* __restrict__ outf,
                                              const float* __restrict__ xorig,
                                              float* __restrict__ x2,
                                              int N, int K) {
    __shared__ ushort lA[128 * 32];   // 8 KB, row-major [128][32], contiguous for load_lds
    __shared__ ushort lB[128 * 32];   // 8 KB
    const int bm = blockIdx.y * 128, bn = blockIdx.x * 128;
    const int tid = threadIdx.x, wave = tid >> 6, lane = tid & 63;
    const int wy = wave >> 1, wx = wave & 1;
    const int lm = lane & 15, quad = lane >> 4;

    f32x4 acc[4][4];
#pragma unroll
    for (int r = 0; r < 4; ++r)
#pragma unroll
        for (int s = 0; s < 4; ++s) acc[r][s] = (f32x4){0.f, 0.f, 0.f, 0.f};

    // staging: chunk c (0..7) of a tile = rows c*16..c*16+15; lane l covers
    // row c*16 + l/4, cols (l&3)*8 -> LDS byte offset c*1024 + l*16 (wave-uniform base + lane*16)
    const int c0 = wave * 2, c1 = wave * 2 + 1;
    const ushort* Ab = A + (size_t)(bm + (lane >> 2)) * lda + (lane & 3) * 8;
    const ushort* Bb = Bt + (size_t)(bn + (lane >> 2)) * ldb + (lane & 3) * 8;
    const size_t a16 = (size_t)16 * lda, b16 = (size_t)16 * ldb;

    for (int k0 = 0; k0 < K; k0 += 32) {
        __builtin_amdgcn_global_load_lds((gmem_void_t*)(Ab + (size_t)c0 * a16 + k0),
                                         (lds_void_t*)&lA[c0 * 512], 16, 0, 0);
        __builtin_amdgcn_global_load_lds((gmem_void_t*)(Ab + (size_t)c1 * a16 + k0),
                                         (lds_void_t*)&lA[c1 * 512], 16, 0, 0);
        __builtin_amdgcn_global_load_lds((gmem_void_t*)(Bb + (size_t)c0 * b16 + k0),
                                         (lds_void_t*)&lB[c0 * 512], 16, 0, 0);
        __builtin_amdgcn_global_load_lds((gmem_void_t*)(Bb + (size_t)c1 * b16 + k0),
                                         (lds_void_t*)&lB[c1 * 512], 16, 0, 0);
        __syncthreads();   // drains vmcnt (global_load_lds) + lgkm

        bf16x8 af[4], bv[4];
#pragma unroll
        for (int r = 0; r < 4; ++r)
            af[r] = *(const bf16x8*)&lA[(wy * 64 + r * 16 + lm) * 32 + quad * 8];
#pragma unroll
        for (int s = 0; s < 4; ++s)
            bv[s] = *(const bf16x8*)&lB[(wx * 64 + s * 16 + lm) * 32 + quad * 8];
#pragma unroll
        for (int r = 0; r < 4; ++r)
#pragma unroll
            for (int s = 0; s < 4; ++s)
                acc[r][s] = __builtin_amdgcn_mfma_f32_16x16x32_bf16(af[r], bv[s], acc[r][s], 0, 0, 0);
        __syncthreads();
    }

#pragma unroll
    for (int s = 0; s < 4; ++s) {
        int col = bn + wx * 64 + s * 16 + lm;
        float bvl = (EPI == EPI_ACC) ? 0.f : bias[col];
#pragma unroll
        for (int r = 0; r < 4; ++r) {
#pragma unroll
            for (int i = 0; i < 4; ++i) {
                int row = bm + wy * 64 + r * 16 + quad * 4 + i;
                float v = acc[r][s][i] + bvl;
                size_t idx = (size_t)row * N + col;
                if constexpr (EPI == EPI_BIAS) {
                    outb[idx] = f2bu(v);
                } else if constexpr (EPI == EPI_GELU) {
                    outb[idx] = f2bu(0.5f * v * (1.f + erff(v * 0.70710678118f)));
                } else if constexpr (EPI == EPI_PROJRES) {
                    x2[idx] = xorig[idx] + v;
                } else if constexpr (EPI == EPI_ACC) {
                    x2[idx] += v;
                } else {
                    outf[idx] = x2[idx] + v;
                }
            }
        }
    }
}

// ---------------- MFMA attention (round-4 kernel, unchanged) ----------------
__global__ __launch_bounds__(256) void attn_k(const ushort* __restrict__ qkv,
                                              const float* __restrict__ qkvb,
                                              const float* __restrict__ relh,
                                              const float* __restrict__ relw,
                                              ushort* __restrict__ aout) {
    const int win = blockIdx.x / NHEADS, head = blockIdx.x % NHEADS;
    const int b = win / 25, wi = win % 25, wr = wi / 5, wc = wi % 5;
    const int hmax = (wr == 4) ? 8 : WINSZ, wmax = (wc == 4) ? 8 : WINSZ;
    const int hoff = head * 64;
    const int tid = threadIdx.x, wave = tid >> 6, lane = tid & 63;
    const int c = lane & 15, quad = lane >> 4;

    __shared__ ushort Ksw[224 * 64];
    __shared__ ushort vTs[64 * 232];
    __shared__ ushort wscr[4][640];

    for (int t = tid; t < 224 * 8; t += 256) {
        int n = t >> 3, ck = t & 7;
        int kh = n >> 4, kw = n & 15;
        union { uint4 u; ushort s[8]; } vals;
        if (kw < WINSZ) {
            if (kh < hmax && kw < wmax) {
                size_t tok = ((size_t)(b * 64 + wr * WINSZ + kh) * 64 + wc * WINSZ + kw);
                union { uint4 u; ushort s[8]; } raw;
                raw.u = *(const uint4*)(qkv + tok * 2304 + 768 + hoff + ck * 8);
#pragma unroll
                for (int j = 0; j < 8; ++j) vals.s[j] = f2bu(0.125f * bfu2f(raw.s[j]));
            } else {
#pragma unroll
                for (int j = 0; j < 8; ++j) vals.s[j] = f2bu(0.125f * qkvb[768 + hoff + ck * 8 + j]);
            }
        } else {
            vals.u = (uint4){0u, 0u, 0u, 0u};
        }
        *(uint4*)&Ksw[n * 64 + ((ck ^ (n & 7)) * 8)] = vals.u;
    }
    for (int u = tid; u < 64 * 28; u += 256) {
        int d = u / 28, kc = u % 28;
        union { uint4 u4; ushort s[8]; } vals;
#pragma unroll
        for (int j = 0; j < 8; ++j) {
            int n = kc * 8 + j, kh = n >> 4, kw = n & 15;
            ushort v = 0;
            if (kw < WINSZ) {
                if (kh < hmax && kw < wmax) {
                    size_t tok = ((size_t)(b * 64 + wr * WINSZ + kh) * 64 + wc * WINSZ + kw);
                    v = qkv[tok * 2304 + 1536 + hoff + d];
                } else {
                    v = f2bu(qkvb[1536 + hoff + d]);
                }
            }
            vals.s[j] = v;
        }
        *(uint4*)&vTs[d * 232 + kc * 8] = vals.u4;
    }
    __syncthreads();

    bf16x8 rhB[2][2], rwB[2][2];
#pragma unroll
    for (int nt = 0; nt < 2; ++nt) {
        int j = nt * 16 + c; if (j > 26) j = 26;
#pragma unroll
        for (int ks = 0; ks < 2; ++ks) {
            const float* ph = relh + (size_t)j * 64 + ks * 32 + quad * 8;
            const float* pw = relw + (size_t)j * 64 + ks * 32 + quad * 8;
            bf16x8 h, w;
#pragma unroll
            for (int e = 0; e < 8; ++e) {
                h[e] = (short)f2bu(ph[e]);
                w[e] = (short)f2bu(pw[e]);
            }
            rhB[nt][ks] = h; rwB[nt][ks] = w;
        }
    }

    ushort* scr = &wscr[wave][0];
    const int lane48 = lane & 48;

    for (int qh = wave; qh < hmax; qh += 4) {
        int qw = c < wmax ? c : (wmax - 1);
        size_t qtok = ((size_t)(b * 64 + wr * WINSZ + qh) * 64 + wc * WINSZ + qw);
        bf16x8 aq0 = *(const bf16x8*)(qkv + qtok * 2304 + hoff + quad * 8);
        bf16x8 aq1 = *(const bf16x8*)(qkv + qtok * 2304 + hoff + 32 + quad * 8);

        f32x4 z = (f32x4){0.f, 0.f, 0.f, 0.f};
        f32x4 dh0 = __builtin_amdgcn_mfma_f32_16x16x32_bf16(aq0, rhB[0][0], z, 0, 0, 0);
        dh0 = __builtin_amdgcn_mfma_f32_16x16x32_bf16(aq1, rhB[0][1], dh0, 0, 0, 0);
        f32x4 dh1 = __builtin_amdgcn_mfma_f32_16x16x32_bf16(aq0, rhB[1][0], z, 0, 0, 0);
        dh1 = __builtin_amdgcn_mfma_f32_16x16x32_bf16(aq1, rhB[1][1], dh1, 0, 0, 0);
        f32x4 dw0 = __builtin_amdgcn_mfma_f32_16x16x32_bf16(aq0, rwB[0][0], z, 0, 0, 0);
        dw0 = __builtin_amdgcn_mfma_f32_16x16x32_bf16(aq1, rwB[0][1], dw0, 0, 0, 0);
        f32x4 dw1 = __builtin_amdgcn_mfma_f32_16x16x32_bf16(aq0, rwB[1][0], z, 0, 0, 0);
        dw1 = __builtin_amdgcn_mfma_f32_16x16x32_bf16(aq1, rwB[1][1], dw1, 0, 0, 0);

#pragma unroll
        for (int i = 0; i < 4; ++i) {
            scr[(quad * 4 + i) * 28 + c] = f2bu(dh0[i]);
            if (c < 12) scr[(quad * 4 + i) * 28 + 16 + c] = f2bu(dh1[i]);
        }

        float bw[4];
#pragma unroll
        for (int i = 0; i < 4; ++i) {
            int m = quad * 4 + i;
            int j = m - c + 13; int jc = j < 0 ? 0 : j;
            int addr = (lane48 | (jc & 15)) << 2;
            int t0 = __builtin_amdgcn_ds_bpermute(addr, __float_as_int(dw0[i]));
            int t1 = __builtin_amdgcn_ds_bpermute(addr, __float_as_int(dw1[i]));
            bw[i] = (jc >= 16) ? __int_as_float(t1) : __int_as_float(t0);
        }

        f32x4 s[14];
#pragma unroll
        for (int kh = 0; kh < 14; ++kh) {
            int n = kh * 16 + c;
            int n7 = n & 7;
            bf16x8 kb0 = *(const bf16x8*)&Ksw[n * 64 + ((0 * 4 + quad) ^ n7) * 8];
            bf16x8 kb1 = *(const bf16x8*)&Ksw[n * 64 + ((1 * 4 + quad) ^ n7) * 8];
            f32x4 acc = __builtin_amdgcn_mfma_f32_16x16x32_bf16(aq0, kb0, z, 0, 0, 0);
            acc = __builtin_amdgcn_mfma_f32_16x16x32_bf16(aq1, kb1, acc, 0, 0, 0);
            int jstar = qh + 13 - kh;
#pragma unroll
            for (int i = 0; i < 4; ++i) {
                float dh = bfu2f(scr[(quad * 4 + i) * 28 + jstar]);
                float v = acc[i] + dh + bw[i];
                acc[i] = (c < WINSZ) ? v : -1e30f;
            }
            s[kh] = acc;
        }

        float inv[4];
#pragma unroll
        for (int i = 0; i < 4; ++i) {
            float mx = s[0][i];
#pragma unroll
            for (int kh = 1; kh < 14; ++kh) mx = fmaxf(mx, s[kh][i]);
            mx = fmaxf(mx, __shfl_xor(mx, 1));
            mx = fmaxf(mx, __shfl_xor(mx, 2));
            mx = fmaxf(mx, __shfl_xor(mx, 4));
            mx = fmaxf(mx, __shfl_xor(mx, 8));
            float sum = 0.f;
#pragma unroll
            for (int kh = 0; kh < 14; ++kh) {
                float e = __expf(s[kh][i] - mx);
                s[kh][i] = e;
                sum += e;
            }
            sum += __shfl_xor(sum, 1);
            sum += __shfl_xor(sum, 2);
            sum += __shfl_xor(sum, 4);
            sum += __shfl_xor(sum, 8);
            inv[i] = 1.f / sum;
        }

        f32x4 o[4] = {z, z, z, z};
#pragma unroll
        for (int cc = 0; cc < 7; ++cc) {
#pragma unroll
            for (int i = 0; i < 4; ++i) {
                scr[(quad * 4 + i) * 40 + c]      = f2bu(s[2 * cc][i] * inv[i]);
                scr[(quad * 4 + i) * 40 + 16 + c] = f2bu(s[2 * cc + 1][i] * inv[i]);
            }
            bf16x8 ap = *(const bf16x8*)&scr[c * 40 + quad * 8];
#pragma unroll
            for (int vt = 0; vt < 4; ++vt) {
                bf16x8 vb = *(const bf16x8*)&vTs[(vt * 16 + c) * 232 + cc * 32 + quad * 8];
                o[vt] = __builtin_amdgcn_mfma_f32_16x16x32_bf16(ap, vb, o[vt], 0, 0, 0);
            }
        }

#pragma unroll
        for (int i = 0; i < 4; ++i) {
            int qwp = quad * 4 + i;
            if (qwp < wmax) {
                size_t otok = ((size_t)(b * 64 + wr * WINSZ + qh) * 64 + wc * WINSZ + qwp);
#pragma unroll
                for (int vt = 0; vt < 4; ++vt)
                    aout[otok * 768 + hoff + vt * 16 + c] = f2bu(o[vt][i]);
            }
        }
    }
}

extern "C" void kernel_launch(void* const* d_in, const int* in_sizes, int n_in,
                              void* d_out, int out_size, void* d_ws, size_t ws_size,
                              hipStream_t stream) {
    const float* x      = (const float*)d_in[0];
    const float* n1g    = (const float*)d_in[1];
    const float* n1b    = (const float*)d_in[2];
    const float* qkv_w  = (const float*)d_in[3];
    const float* qkv_b  = (const float*)d_in[4];
    const float* proj_w = (const float*)d_in[5];
    const float* proj_b = (const float*)d_in[6];
    const float* relh   = (const float*)d_in[7];
    const float* relw   = (const float*)d_in[8];
    const float* n2g    = (const float*)d_in[9];
    const float* n2b    = (const float*)d_in[10];
    const float* w1     = (const float*)d_in[11];
    const float* b1     = (const float*)d_in[12];
    const float* w2     = (const float*)d_in[13];
    const float* b2     = (const float*)d_in[14];
    float* out = (float*)d_out;

    char* ws = (char*)d_ws;
    size_t off = 0;
    auto alloc = [&](size_t bytes) -> void* {
        void* p = ws + off;
        off += (bytes + 255) & ~(size_t)255;
        return p;
    };

    ushort* lnbuf  = (ushort*)alloc((size_t)TOKENS * DIMC * 2);    // LN1 out / aout / LN2 out
    ushort* qkvbuf = (ushort*)alloc((size_t)TOKENS * 2304 * 2);    // qkv, later MLP hidden chunk
    float* x2      = (float*)alloc((size_t)TOKENS * DIMC * 4);     // fp32 residual + MLP acc
    ushort* qkvT   = (ushort*)alloc((size_t)2304 * 768 * 2);
    ushort* projT  = (ushort*)alloc((size_t)768 * 768 * 2);
    ushort* w1T    = (ushort*)alloc((size_t)3072 * 768 * 2);
    ushort* w2T    = (ushort*)alloc((size_t)768 * 3072 * 2);
    ushort* aout   = lnbuf;
    ushort* hc     = qkvbuf;   // 16384x1536 bf16 = 50.3 MB fits in 75.5 MB region

    transpose_k<<<(768 * 2304 + 255) / 256, 256, 0, stream>>>(qkv_w, qkvT, 768, 2304);
    transpose_k<<<(768 * 768 + 255) / 256, 256, 0, stream>>>(proj_w, projT, 768, 768);
    transpose_k<<<(768 * 3072 + 255) / 256, 256, 0, stream>>>(w1, w1T, 768, 3072);
    transpose_k<<<(3072 * 768 + 255) / 256, 256, 0, stream>>>(w2, w2T, 3072, 768);

    ln_k<<<TOKENS, 256, 0, stream>>>(x, n1g, n1b, lnbuf);

    dim3 gq(2304 / 128, TOKENS / 128);
    gemm_k<EPI_BIAS><<<gq, 256, 0, stream>>>(lnbuf, DIMC, qkvT, DIMC, qkv_b, qkvbuf,
                                             nullptr, nullptr, nullptr, 2304, DIMC);

    attn_k<<<100 * NHEADS, 256, 0, stream>>>(qkvbuf, qkv_b, relh, relw, aout);

    dim3 gp(DIMC / 128, TOKENS / 128);
    gemm_k<EPI_PROJRES><<<gp, 256, 0, stream>>>(aout, DIMC, projT, DIMC, proj_b, nullptr,
                                                nullptr, x, x2, DIMC, DIMC);

    ln_k<<<TOKENS, 256, 0, stream>>>(x2, n2g, n2b, lnbuf);

    dim3 gh(1536 / 128, TOKENS / 128);
    for (int c = 0; c < 2; ++c) {
        gemm_k<EPI_GELU><<<gh, 256, 0, stream>>>(lnbuf, DIMC, w1T + (size_t)c * 1536 * 768, DIMC,
                                                 b1 + c * 1536, hc, nullptr, nullptr, nullptr,
                                                 1536, DIMC);
        if (c == 0)
            gemm_k<EPI_ACC><<<gp, 256, 0, stream>>>(hc, 1536, w2T + (size_t)c * 1536, 3072,
                                                    b2, nullptr, nullptr, nullptr, x2, DIMC, 1536);
        else
            gemm_k<EPI_RESOUT><<<gp, 256, 0, stream>>>(hc, 1536, w2T + (size_t)c * 1536, 3072,
                                                       b2, nullptr, out, nullptr, x2, DIMC, 1536);
    }
}

// Round 6
// 710.529 us; speedup vs baseline: 3.9521x; 1.0893x over previous
//
#include <hip/hip_runtime.h>
#include <hip/hip_bf16.h>
#include <math.h>

#define DIMC 768
#define NHEADS 12
#define WINSZ 14
#define NTOK 196
#define TOKENS 16384

using bf = __hip_bfloat16;
typedef __attribute__((ext_vector_type(4))) float f32x4;
typedef __attribute__((ext_vector_type(8))) short bf16x8;

typedef __attribute__((address_space(3))) void lds_void_t;
typedef const __attribute__((address_space(1))) void gmem_void_t;

__device__ inline float bfu2f(ushort u) { return __uint_as_float((uint)u << 16); }
__device__ inline ushort f2bu(float f) {
    bf t = __float2bfloat16(f);
    return __builtin_bit_cast(ushort, t);
}

// ---------------- weight transpose + fp32 -> bf16 convert (tiny) ----------------
__global__ __launch_bounds__(256) void transpose_k(const float* __restrict__ in,
                                                   ushort* __restrict__ out, int R, int C) {
    long i = (long)blockIdx.x * 256 + threadIdx.x;
    if (i >= (long)R * C) return;
    int r = (int)(i / C), c = (int)(i % C);
    out[(long)c * R + r] = f2bu(in[i]);
}

// ---------------- layernorm fp32 in, bf16 out ----------------
__device__ inline float blk_sum(float v, float* wred, int tid) {
    for (int m = 32; m; m >>= 1) v += __shfl_xor(v, m);
    if ((tid & 63) == 0) wred[tid >> 6] = v;
    __syncthreads();
    float r = wred[0] + wred[1] + wred[2] + wred[3];
    __syncthreads();
    return r;
}

__global__ __launch_bounds__(256) void ln_k(const float* __restrict__ x, const float* __restrict__ g,
                                            const float* __restrict__ bb, ushort* __restrict__ out) {
    int row = blockIdx.x, tid = threadIdx.x;
    const float* xr = x + (size_t)row * DIMC;
    __shared__ float wred[4];
    float v0 = xr[tid], v1 = xr[tid + 256], v2 = xr[tid + 512];
    float mean = blk_sum(v0 + v1 + v2, wred, tid) * (1.f / 768.f);
    float d0 = v0 - mean, d1 = v1 - mean, d2 = v2 - mean;
    float var = blk_sum(d0 * d0 + d1 * d1 + d2 * d2, wred, tid) * (1.f / 768.f);
    float rs = rsqrtf(var + 1e-5f);
    ushort* o = out + (size_t)row * DIMC;
    o[tid]       = f2bu(d0 * rs * g[tid]       + bb[tid]);
    o[tid + 256] = f2bu(d1 * rs * g[tid + 256] + bb[tid + 256]);
    o[tid + 512] = f2bu(d2 * rs * g[tid + 512] + bb[tid + 512]);
}

// ---------------- bf16 MFMA GEMM: 128x128 tile, BK=64 (two BK=32 half-buffers) ----------------
// M,N multiples of 128; K multiple of 64. Bt pre-transposed [N][K] bf16. Bias fp32.
enum { EPI_BIAS = 0, EPI_GELU = 1, EPI_PROJRES = 2, EPI_ACC = 3, EPI_RESOUT = 4 };

template <int EPI>
__global__ __launch_bounds__(256) void gemm_k(const ushort* __restrict__ A, int lda,
                                              const ushort* __restrict__ Bt, int ldb,
                                              const float* __restrict__ bias,
                                              ushort* __restrict__ outb,
                                              float* __restrict__ outf,
                                              const float* __restrict__ xorig,
                                              float* __restrict__ x2,
                                              int N, int K) {
    __shared__ ushort lA0[128 * 32];   // k-half 0: rows [128][32], 2-way-free banking
    __shared__ ushort lA1[128 * 32];   // k-half 1
    __shared__ ushort lB0[128 * 32];
    __shared__ ushort lB1[128 * 32];
    const int bm = blockIdx.y * 128, bn = blockIdx.x * 128;
    const int tid = threadIdx.x, wave = tid >> 6, lane = tid & 63;
    const int wy = wave >> 1, wx = wave & 1;
    const int lm = lane & 15, quad = lane >> 4;

    f32x4 acc[4][4];
#pragma unroll
    for (int r = 0; r < 4; ++r)
#pragma unroll
        for (int s = 0; s < 4; ++s) acc[r][s] = (f32x4){0.f, 0.f, 0.f, 0.f};

    // chunk = 16 rows x 32 cols = 1024 B; lane l -> row l>>2, col (l&3)*8 -> LDS byte l*16
    const int c0 = wave * 2, c1 = wave * 2 + 1;
    const ushort* Ab = A + (size_t)(bm + (lane >> 2)) * lda + (lane & 3) * 8;
    const ushort* Bb = Bt + (size_t)(bn + (lane >> 2)) * ldb + (lane & 3) * 8;
    const size_t a16 = (size_t)16 * lda, b16 = (size_t)16 * ldb;

    for (int k0 = 0; k0 < K; k0 += 64) {
        __builtin_amdgcn_global_load_lds((gmem_void_t*)(Ab + (size_t)c0 * a16 + k0),
                                         (lds_void_t*)&lA0[c0 * 512], 16, 0, 0);
        __builtin_amdgcn_global_load_lds((gmem_void_t*)(Ab + (size_t)c0 * a16 + k0 + 32),
                                         (lds_void_t*)&lA1[c0 * 512], 16, 0, 0);
        __builtin_amdgcn_global_load_lds((gmem_void_t*)(Ab + (size_t)c1 * a16 + k0),
                                         (lds_void_t*)&lA0[c1 * 512], 16, 0, 0);
        __builtin_amdgcn_global_load_lds((gmem_void_t*)(Ab + (size_t)c1 * a16 + k0 + 32),
                                         (lds_void_t*)&lA1[c1 * 512], 16, 0, 0);
        __builtin_amdgcn_global_load_lds((gmem_void_t*)(Bb + (size_t)c0 * b16 + k0),
                                         (lds_void_t*)&lB0[c0 * 512], 16, 0, 0);
        __builtin_amdgcn_global_load_lds((gmem_void_t*)(Bb + (size_t)c0 * b16 + k0 + 32),
                                         (lds_void_t*)&lB1[c0 * 512], 16, 0, 0);
        __builtin_amdgcn_global_load_lds((gmem_void_t*)(Bb + (size_t)c1 * b16 + k0),
                                         (lds_void_t*)&lB0[c1 * 512], 16, 0, 0);
        __builtin_amdgcn_global_load_lds((gmem_void_t*)(Bb + (size_t)c1 * b16 + k0 + 32),
                                         (lds_void_t*)&lB1[c1 * 512], 16, 0, 0);
        __syncthreads();   // drains vmcnt (global_load_lds)

        bf16x8 af0[4], af1[4], bv0[4], bv1[4];
#pragma unroll
        for (int r = 0; r < 4; ++r) {
            af0[r] = *(const bf16x8*)&lA0[(wy * 64 + r * 16 + lm) * 32 + quad * 8];
            af1[r] = *(const bf16x8*)&lA1[(wy * 64 + r * 16 + lm) * 32 + quad * 8];
        }
#pragma unroll
        for (int s = 0; s < 4; ++s) {
            bv0[s] = *(const bf16x8*)&lB0[(wx * 64 + s * 16 + lm) * 32 + quad * 8];
            bv1[s] = *(const bf16x8*)&lB1[(wx * 64 + s * 16 + lm) * 32 + quad * 8];
        }
#pragma unroll
        for (int r = 0; r < 4; ++r)
#pragma unroll
            for (int s = 0; s < 4; ++s) {
                acc[r][s] = __builtin_amdgcn_mfma_f32_16x16x32_bf16(af0[r], bv0[s], acc[r][s], 0, 0, 0);
                acc[r][s] = __builtin_amdgcn_mfma_f32_16x16x32_bf16(af1[r], bv1[s], acc[r][s], 0, 0, 0);
            }
        __syncthreads();
    }

#pragma unroll
    for (int s = 0; s < 4; ++s) {
        int col = bn + wx * 64 + s * 16 + lm;
        float bvl = (EPI == EPI_ACC) ? 0.f : bias[col];
#pragma unroll
        for (int r = 0; r < 4; ++r) {
#pragma unroll
            for (int i = 0; i < 4; ++i) {
                int row = bm + wy * 64 + r * 16 + quad * 4 + i;
                float v = acc[r][s][i] + bvl;
                size_t idx = (size_t)row * N + col;
                if constexpr (EPI == EPI_BIAS) {
                    outb[idx] = f2bu(v);
                } else if constexpr (EPI == EPI_GELU) {
                    outb[idx] = f2bu(0.5f * v * (1.f + erff(v * 0.70710678118f)));
                } else if constexpr (EPI == EPI_PROJRES) {
                    x2[idx] = xorig[idx] + v;
                } else if constexpr (EPI == EPI_ACC) {
                    x2[idx] += v;
                } else {
                    outf[idx] = x2[idx] + v;
                }
            }
        }
    }
}

// ---------------- MFMA attention: one block per (window, head), 4 waves ----------------
__global__ __launch_bounds__(256) void attn_k(const ushort* __restrict__ qkv,
                                              const float* __restrict__ qkvb,
                                              const float* __restrict__ relh,
                                              const float* __restrict__ relw,
                                              ushort* __restrict__ aout) {
    const int win = blockIdx.x / NHEADS, head = blockIdx.x % NHEADS;
    const int b = win / 25, wi = win % 25, wr = wi / 5, wc = wi % 5;
    const int hmax = (wr == 4) ? 8 : WINSZ, wmax = (wc == 4) ? 8 : WINSZ;
    const int hoff = head * 64;
    const int tid = threadIdx.x, wave = tid >> 6, lane = tid & 63;
    const int c = lane & 15, quad = lane >> 4;

    __shared__ ushort Ksw[224 * 64];     // K raw (unscaled), chunk-XOR swizzled (28 KB)
    __shared__ ushort vTs[64 * 264];     // V^T, stride 264 + chunk-XOR swizzle (33 KB)
    __shared__ ushort wscr[4][640];      // per-wave scratch

    // ---- stage K: pure uint4 copy (scale applied in S epilogue) ----
    for (int t = tid; t < 224 * 8; t += 256) {
        int n = t >> 3, ck = t & 7;
        int kh = n >> 4, kw = n & 15;
        uint4 vals;
        if (kw < WINSZ && kh < hmax && kw < wmax) {
            size_t tok = ((size_t)(b * 64 + wr * WINSZ + kh) * 64 + wc * WINSZ + kw);
            vals = *(const uint4*)(qkv + tok * 2304 + 768 + hoff + ck * 8);
        } else if (kw < WINSZ) {  // pad token inside window: k = qkv bias slice
            union { uint4 u; ushort s[8]; } tmp;
#pragma unroll
            for (int j = 0; j < 8; ++j) tmp.s[j] = f2bu(qkvb[768 + hoff + ck * 8 + j]);
            vals = tmp.u;
        } else {
            vals = (uint4){0u, 0u, 0u, 0u};
        }
        *(uint4*)&Ksw[n * 64 + ((ck ^ (n & 7)) * 8)] = vals;
    }
    // ---- stage V^T: coalesced uint4 row reads + swizzled transposed LDS writes ----
    for (int t = tid; t < 224 * 8; t += 256) {
        int n = t >> 3, dg = t & 7;
        int kh = n >> 4, kw = n & 15;
        union { uint4 u; ushort s[8]; } vals;
        if (kw < WINSZ && kh < hmax && kw < wmax) {
            size_t tok = ((size_t)(b * 64 + wr * WINSZ + kh) * 64 + wc * WINSZ + kw);
            vals.u = *(const uint4*)(qkv + tok * 2304 + 1536 + hoff + dg * 8);
        } else if (kw < WINSZ) {
#pragma unroll
            for (int j = 0; j < 8; ++j) vals.s[j] = f2bu(qkvb[1536 + hoff + dg * 8 + j]);
        } else {
            vals.u = (uint4){0u, 0u, 0u, 0u};   // P=0 there; any finite value ok
        }
        int kchunk = n >> 3;
#pragma unroll
        for (int j = 0; j < 8; ++j) {
            int d = dg * 8 + j;
            vTs[d * 264 + ((kchunk ^ dg) * 8) + (n & 7)] = vals.s[j];
        }
    }
    __syncthreads();   // the ONLY block barrier

    bf16x8 rhB[2][2], rwB[2][2];
#pragma unroll
    for (int nt = 0; nt < 2; ++nt) {
        int j = nt * 16 + c; if (j > 26) j = 26;
#pragma unroll
        for (int ks = 0; ks < 2; ++ks) {
            const float* ph = relh + (size_t)j * 64 + ks * 32 + quad * 8;
            const float* pw = relw + (size_t)j * 64 + ks * 32 + quad * 8;
            bf16x8 h, w;
#pragma unroll
            for (int e = 0; e < 8; ++e) {
                h[e] = (short)f2bu(ph[e]);
                w[e] = (short)f2bu(pw[e]);
            }
            rhB[nt][ks] = h; rwB[nt][ks] = w;
        }
    }

    ushort* scr = &wscr[wave][0];
    const int lane48 = lane & 48;

    for (int qh = wave; qh < hmax; qh += 4) {
        int qw = c < wmax ? c : (wmax - 1);
        size_t qtok = ((size_t)(b * 64 + wr * WINSZ + qh) * 64 + wc * WINSZ + qw);
        bf16x8 aq0 = *(const bf16x8*)(qkv + qtok * 2304 + hoff + quad * 8);
        bf16x8 aq1 = *(const bf16x8*)(qkv + qtok * 2304 + hoff + 32 + quad * 8);

        f32x4 z = (f32x4){0.f, 0.f, 0.f, 0.f};
        f32x4 dh0 = __builtin_amdgcn_mfma_f32_16x16x32_bf16(aq0, rhB[0][0], z, 0, 0, 0);
        dh0 = __builtin_amdgcn_mfma_f32_16x16x32_bf16(aq1, rhB[0][1], dh0, 0, 0, 0);
        f32x4 dh1 = __builtin_amdgcn_mfma_f32_16x16x32_bf16(aq0, rhB[1][0], z, 0, 0, 0);
        dh1 = __builtin_amdgcn_mfma_f32_16x16x32_bf16(aq1, rhB[1][1], dh1, 0, 0, 0);
        f32x4 dw0 = __builtin_amdgcn_mfma_f32_16x16x32_bf16(aq0, rwB[0][0], z, 0, 0, 0);
        dw0 = __builtin_amdgcn_mfma_f32_16x16x32_bf16(aq1, rwB[0][1], dw0, 0, 0, 0);
        f32x4 dw1 = __builtin_amdgcn_mfma_f32_16x16x32_bf16(aq0, rwB[1][0], z, 0, 0, 0);
        dw1 = __builtin_amdgcn_mfma_f32_16x16x32_bf16(aq1, rwB[1][1], dw1, 0, 0, 0);

#pragma unroll
        for (int i = 0; i < 4; ++i) {
            scr[(quad * 4 + i) * 28 + c] = f2bu(dh0[i]);
            if (c < 12) scr[(quad * 4 + i) * 28 + 16 + c] = f2bu(dh1[i]);
        }

        float bw[4];
#pragma unroll
        for (int i = 0; i < 4; ++i) {
            int m = quad * 4 + i;
            int j = m - c + 13; int jc = j < 0 ? 0 : j;
            int addr = (lane48 | (jc & 15)) << 2;
            int t0 = __builtin_amdgcn_ds_bpermute(addr, __float_as_int(dw0[i]));
            int t1 = __builtin_amdgcn_ds_bpermute(addr, __float_as_int(dw1[i]));
            bw[i] = (jc >= 16) ? __int_as_float(t1) : __int_as_float(t0);
        }

        f32x4 s[14];
#pragma unroll
        for (int kh = 0; kh < 14; ++kh) {
            int n = kh * 16 + c;
            int n7 = n & 7;
            bf16x8 kb0 = *(const bf16x8*)&Ksw[n * 64 + ((0 * 4 + quad) ^ n7) * 8];
            bf16x8 kb1 = *(const bf16x8*)&Ksw[n * 64 + ((1 * 4 + quad) ^ n7) * 8];
            f32x4 acc = __builtin_amdgcn_mfma_f32_16x16x32_bf16(aq0, kb0, z, 0, 0, 0);
            acc = __builtin_amdgcn_mfma_f32_16x16x32_bf16(aq1, kb1, acc, 0, 0, 0);
            int jstar = qh + 13 - kh;
#pragma unroll
            for (int i = 0; i < 4; ++i) {
                float dh = bfu2f(scr[(quad * 4 + i) * 28 + jstar]);
                float v = fmaf(0.125f, acc[i], dh + bw[i]);
                acc[i] = (c < WINSZ) ? v : -1e30f;
            }
            s[kh] = acc;
        }

        float inv[4];
#pragma unroll
        for (int i = 0; i < 4; ++i) {
            float mx = s[0][i];
#pragma unroll
            for (int kh = 1; kh < 14; ++kh) mx = fmaxf(mx, s[kh][i]);
            mx = fmaxf(mx, __shfl_xor(mx, 1));
            mx = fmaxf(mx, __shfl_xor(mx, 2));
            mx = fmaxf(mx, __shfl_xor(mx, 4));
            mx = fmaxf(mx, __shfl_xor(mx, 8));
            float sum = 0.f;
#pragma unroll
            for (int kh = 0; kh < 14; ++kh) {
                float e = __expf(s[kh][i] - mx);
                s[kh][i] = e;
                sum += e;
            }
            sum += __shfl_xor(sum, 1);
            sum += __shfl_xor(sum, 2);
            sum += __shfl_xor(sum, 4);
            sum += __shfl_xor(sum, 8);
            inv[i] = 1.f / sum;
        }

        f32x4 o[4] = {z, z, z, z};
#pragma unroll
        for (int cc = 0; cc < 7; ++cc) {
#pragma unroll
            for (int i = 0; i < 4; ++i) {
                scr[(quad * 4 + i) * 40 + c]      = f2bu(s[2 * cc][i] * inv[i]);
                scr[(quad * 4 + i) * 40 + 16 + c] = f2bu(s[2 * cc + 1][i] * inv[i]);
            }
            bf16x8 ap = *(const bf16x8*)&scr[c * 40 + quad * 8];
#pragma unroll
            for (int vt = 0; vt < 4; ++vt) {
                int d = vt * 16 + c;
                int dgr = (d >> 3) & 7;
                bf16x8 vb = *(const bf16x8*)&vTs[d * 264 + (((cc * 4 + quad) ^ dgr) * 8)];
                o[vt] = __builtin_amdgcn_mfma_f32_16x16x32_bf16(ap, vb, o[vt], 0, 0, 0);
            }
        }

#pragma unroll
        for (int i = 0; i < 4; ++i) {
            int qwp = quad * 4 + i;
            if (qwp < wmax) {
                size_t otok = ((size_t)(b * 64 + wr * WINSZ + qh) * 64 + wc * WINSZ + qwp);
#pragma unroll
                for (int vt = 0; vt < 4; ++vt)
                    aout[otok * 768 + hoff + vt * 16 + c] = f2bu(o[vt][i]);
            }
        }
    }
}

extern "C" void kernel_launch(void* const* d_in, const int* in_sizes, int n_in,
                              void* d_out, int out_size, void* d_ws, size_t ws_size,
                              hipStream_t stream) {
    const float* x      = (const float*)d_in[0];
    const float* n1g    = (const float*)d_in[1];
    const float* n1b    = (const float*)d_in[2];
    const float* qkv_w  = (const float*)d_in[3];
    const float* qkv_b  = (const float*)d_in[4];
    const float* proj_w = (const float*)d_in[5];
    const float* proj_b = (const float*)d_in[6];
    const float* relh   = (const float*)d_in[7];
    const float* relw   = (const float*)d_in[8];
    const float* n2g    = (const float*)d_in[9];
    const float* n2b    = (const float*)d_in[10];
    const float* w1     = (const float*)d_in[11];
    const float* b1     = (const float*)d_in[12];
    const float* w2     = (const float*)d_in[13];
    const float* b2     = (const float*)d_in[14];
    float* out = (float*)d_out;

    char* ws = (char*)d_ws;
    size_t off = 0;
    auto alloc = [&](size_t bytes) -> void* {
        void* p = ws + off;
        off += (bytes + 255) & ~(size_t)255;
        return p;
    };

    ushort* lnbuf  = (ushort*)alloc((size_t)TOKENS * DIMC * 2);
    ushort* qkvbuf = (ushort*)alloc((size_t)TOKENS * 2304 * 2);
    float* x2      = (float*)alloc((size_t)TOKENS * DIMC * 4);
    ushort* qkvT   = (ushort*)alloc((size_t)2304 * 768 * 2);
    ushort* projT  = (ushort*)alloc((size_t)768 * 768 * 2);
    ushort* w1T    = (ushort*)alloc((size_t)3072 * 768 * 2);
    ushort* w2T    = (ushort*)alloc((size_t)768 * 3072 * 2);
    ushort* aout   = lnbuf;
    ushort* hc     = qkvbuf;

    transpose_k<<<(768 * 2304 + 255) / 256, 256, 0, stream>>>(qkv_w, qkvT, 768, 2304);
    transpose_k<<<(768 * 768 + 255) / 256, 256, 0, stream>>>(proj_w, projT, 768, 768);
    transpose_k<<<(768 * 3072 + 255) / 256, 256, 0, stream>>>(w1, w1T, 768, 3072);
    transpose_k<<<(3072 * 768 + 255) / 256, 256, 0, stream>>>(w2, w2T, 3072, 768);

    ln_k<<<TOKENS, 256, 0, stream>>>(x, n1g, n1b, lnbuf);

    dim3 gq(2304 / 128, TOKENS / 128);
    gemm_k<EPI_BIAS><<<gq, 256, 0, stream>>>(lnbuf, DIMC, qkvT, DIMC, qkv_b, qkvbuf,
                                             nullptr, nullptr, nullptr, 2304, DIMC);

    attn_k<<<100 * NHEADS, 256, 0, stream>>>(qkvbuf, qkv_b, relh, relw, aout);

    dim3 gp(DIMC / 128, TOKENS / 128);
    gemm_k<EPI_PROJRES><<<gp, 256, 0, stream>>>(aout, DIMC, projT, DIMC, proj_b, nullptr,
                                                nullptr, x, x2, DIMC, DIMC);

    ln_k<<<TOKENS, 256, 0, stream>>>(x2, n2g, n2b, lnbuf);

    dim3 gh(1536 / 128, TOKENS / 128);
    for (int c = 0; c < 2; ++c) {
        gemm_k<EPI_GELU><<<gh, 256, 0, stream>>>(lnbuf, DIMC, w1T + (size_t)c * 1536 * 768, DIMC,
                                                 b1 + c * 1536, hc, nullptr, nullptr, nullptr,
                                                 1536, DIMC);
        if (c == 0)
            gemm_k<EPI_ACC><<<gp, 256, 0, stream>>>(hc, 1536, w2T + (size_t)c * 1536, 3072,
                                                    b2, nullptr, nullptr, nullptr, x2, DIMC, 1536);
        else
            gemm_k<EPI_RESOUT><<<gp, 256, 0, stream>>>(hc, 1536, w2T + (size_t)c * 1536, 3072,
                                                       b2, nullptr, out, nullptr, x2, DIMC, 1536);
    }
}